// Round 3
// baseline (492.371 us; speedup 1.0000x reference)
//
#include <hip/hip_runtime.h>

// BeliefPropagationVC: out[b,e] = 0.5 * ( llr_weight[e%NV]*llr[b,e%NV]
//                                        + sum_k input[b,k] * mask[e,k]*W[e,k] )
// B=32, E=8192, NV=2048. mask density ~8/8192 => ~8 nnz per row (Poisson).
//
// R3 design: WAVE-synchronous, zero barriers, zero LDS. One 64-lane wave per
// row. The wave scans its 32 KB mask row in 4 rounds of 8 in-flight uint4
// loads (max MLP, no consumers between loads). Nonzeros located via __ballot;
// (col, maskval) broadcast with __shfl; all lanes process each hit together
// (lane handles batch lane&31; the two 32-lane halves duplicate -- broadcast
// loads make that free). acc lives in a register. Epilogue: analytic
// llr_expander (one-hot of e % 2048); lanes 0-31 write the output column.

#define N_VAR  2048
#define N_EDGE 8192
#define BATCH  32
#define BLOCK  256   // 4 waves per block, one row per wave

__global__ __launch_bounds__(BLOCK) void bp_vc_kernel(
    const float* __restrict__ input,   // [B, E]
    const float* __restrict__ weight,  // [E, E]
    const float* __restrict__ mask,    // [E, E]
    const float* __restrict__ llr,     // [B, NV]
    const float* __restrict__ llr_w,   // [NV]
    float* __restrict__ out)           // [B, E]
{
    const int wave = threadIdx.x >> 6;
    const int lane = threadIdx.x & 63;
    const int row  = blockIdx.x * (BLOCK / 64) + wave;
    const int b    = lane & (BATCH - 1);

    const uint4* __restrict__ mrow = (const uint4*)(mask + (size_t)row * N_EDGE);
    const float* __restrict__ wrow = weight + (size_t)row * N_EDGE;

    float acc = 0.0f;

    // 8192 floats = 2048 uint4 = 32 uint4/lane, in 4 rounds of 8 in flight.
    #pragma unroll
    for (int round = 0; round < 4; ++round) {
        uint4 m[8];
        #pragma unroll
        for (int r = 0; r < 8; ++r)
            m[r] = mrow[(round * 8 + r) * 64 + lane];   // independent loads

        #pragma unroll
        for (int r = 0; r < 8; ++r) {
            const uint4 v = m[r];
            unsigned long long hits = __ballot((v.x | v.y | v.z | v.w) != 0u);
            while (hits) {                               // wave-uniform loop
                const int src = __builtin_ctzll(hits);
                hits &= hits - 1;
                const unsigned hv[4] = {
                    (unsigned)__shfl((int)v.x, src),
                    (unsigned)__shfl((int)v.y, src),
                    (unsigned)__shfl((int)v.z, src),
                    (unsigned)__shfl((int)v.w, src),
                };
                const int col0 = ((round * 8 + r) * 64 + src) * 4;
                #pragma unroll
                for (int j = 0; j < 4; ++j) {
                    if (hv[j] != 0u) {                   // uniform branch
                        const int col = col0 + j;
                        const float w = __uint_as_float(hv[j]) * wrow[col];
                        acc = fmaf(w, input[(size_t)b * N_EDGE + col], acc);
                    }
                }
            }
        }
    }

    // Epilogue: lanes 0-31 write out[:, row] (halves computed identical acc).
    if (lane < BATCH) {
        const int v = row & (N_VAR - 1);   // llr_expander = one-hot(e % 2048)
        const float llr_term = llr_w[v] * llr[(size_t)b * N_VAR + v];
        out[(size_t)b * N_EDGE + row] = 0.5f * (acc + llr_term);
    }
}

extern "C" void kernel_launch(void* const* d_in, const int* in_sizes, int n_in,
                              void* d_out, int out_size, void* d_ws, size_t ws_size,
                              hipStream_t stream) {
    const float* input  = (const float*)d_in[0];  // [32, 8192]
    const float* weight = (const float*)d_in[1];  // [8192, 8192]
    const float* mask   = (const float*)d_in[2];  // [8192, 8192]
    const float* llr    = (const float*)d_in[3];  // [32, 2048]
    const float* llr_w  = (const float*)d_in[4];  // [1, 2048]
    // d_in[5] = llr_expander, analytic (one-hot of e % 2048), not read.
    float* out = (float*)d_out;                   // [32, 8192]

    bp_vc_kernel<<<N_EDGE / (BLOCK / 64), BLOCK, 0, stream>>>(
        input, weight, mask, llr, llr_w, out);
}

// Round 5
// 486.964 us; speedup vs baseline: 1.0111x; 1.0111x over previous
//
#include <hip/hip_runtime.h>

// BeliefPropagationVC: out[b,e] = 0.5 * ( llr_weight[e%NV]*llr[b,e%NV]
//                                        + sum_k input[b,k] * mask[e,k]*W[e,k] )
// B=32, E=8192, NV=2048. mask density ~8/8192 => ~8 nnz per row (Poisson).
//
// R5 = R4 with the compile fix: __builtin_nontemporal_load needs a native
// clang vector type, not HIP_vector_type. Design: wave-per-row, zero
// barriers/LDS; hit lanes gather their own weight in ONE exec-masked vmem op
// and pre-multiply s = mval*w; the uniform per-hit loop is then only
// 2 shfl + one L2-resident input gather + fma. Nontemporal mask loads keep
// L2 for the reused 1 MB input.

#define N_VAR  2048
#define N_EDGE 8192
#define BATCH  32
#define BLOCK  256   // 4 waves per block, one row per wave

typedef unsigned int u32x4 __attribute__((ext_vector_type(4)));

__global__ __launch_bounds__(BLOCK) void bp_vc_kernel(
    const float* __restrict__ input,   // [B, E]
    const float* __restrict__ weight,  // [E, E]
    const float* __restrict__ mask,    // [E, E]
    const float* __restrict__ llr,     // [B, NV]
    const float* __restrict__ llr_w,   // [NV]
    float* __restrict__ out)           // [B, E]
{
    const int wave = threadIdx.x >> 6;
    const int lane = threadIdx.x & 63;
    const int row  = blockIdx.x * (BLOCK / 64) + wave;
    const int b    = lane & (BATCH - 1);

    const u32x4* __restrict__ mrow = (const u32x4*)(mask + (size_t)row * N_EDGE);
    const float* __restrict__ wrow = weight + (size_t)row * N_EDGE;

    float acc = 0.0f;

    // 8192 floats = 2048 uint4 = 32 uint4/lane, in 4 rounds of 8 in flight.
    #pragma unroll
    for (int round = 0; round < 4; ++round) {
        u32x4 m[8];
        #pragma unroll
        for (int r = 0; r < 8; ++r)
            m[r] = __builtin_nontemporal_load(
                       &mrow[(round * 8 + r) * 64 + lane]);

        #pragma unroll
        for (int r = 0; r < 8; ++r) {
            const u32x4 v = m[r];
            if (__ballot((v.x | v.y | v.z | v.w) != 0u)) {   // uniform skip
                const int colbase = ((round * 8 + r) * 64 + lane) * 4;
                const unsigned c[4] = { v.x, v.y, v.z, v.w };
                #pragma unroll
                for (int j = 0; j < 4; ++j) {
                    const bool hit = (c[j] != 0u);
                    unsigned long long bal = __ballot(hit);
                    if (bal) {
                        // parallel weight gather: every hit lane loads its own
                        // w[col] in ONE exec-masked vmem op (no serial drains)
                        const int col = colbase + j;
                        float s = 0.0f;
                        if (hit)
                            s = __uint_as_float(c[j]) * wrow[col];
                        // broadcast hits; VALU + L2 gather only
                        while (bal) {
                            const int src = (int)__builtin_ctzll(bal);
                            bal &= bal - 1;
                            const float sb = __shfl(s, src);
                            const int   cb = __shfl(col, src);
                            acc = fmaf(sb, input[(size_t)b * N_EDGE + cb], acc);
                        }
                    }
                }
            }
        }
    }

    // Epilogue: lanes 0-31 write out[:, row] (halves computed identical acc).
    if (lane < BATCH) {
        const int v = row & (N_VAR - 1);   // llr_expander = one-hot(e % 2048)
        const float llr_term = llr_w[v] * llr[(size_t)b * N_VAR + v];
        out[(size_t)b * N_EDGE + row] = 0.5f * (acc + llr_term);
    }
}

extern "C" void kernel_launch(void* const* d_in, const int* in_sizes, int n_in,
                              void* d_out, int out_size, void* d_ws, size_t ws_size,
                              hipStream_t stream) {
    const float* input  = (const float*)d_in[0];  // [32, 8192]
    const float* weight = (const float*)d_in[1];  // [8192, 8192]
    const float* mask   = (const float*)d_in[2];  // [8192, 8192]
    const float* llr    = (const float*)d_in[3];  // [32, 2048]
    const float* llr_w  = (const float*)d_in[4];  // [1, 2048]
    // d_in[5] = llr_expander, analytic (one-hot of e % 2048), not read.
    float* out = (float*)d_out;                   // [32, 8192]

    bp_vc_kernel<<<N_EDGE / (BLOCK / 64), BLOCK, 0, stream>>>(
        input, weight, mask, llr, llr_w, out);
}